// Round 2
// baseline (208.025 us; speedup 1.0000x reference)
//
#include <hip/hip_runtime.h>
#include <hip/hip_cooperative_groups.h>
#include <stdint.h>

namespace cg = cooperative_groups;

#define GXC 512
#define GYC 512
#define GXY (GXC * GYC)     // 262144 voxels per batch
#define NB  512             // place blocks
#define SC  8192            // points per block = one flush (FPB=1)
#define PT  1024            // place threads per block
#define SPT (SC / PT)       // staged points per thread = 8
#define LBINS 512           // local bins = GXC (chunk stays inside one batch)
#define XG  4               // bins per reduce group
#define BPB (GXY / 256)     // fallback fill blocks per batch = 1024

typedef float v4f __attribute__((ext_vector_type(4)));
typedef int   v2i __attribute__((ext_vector_type(2)));

// ---- monotone float <-> sortable-uint mapping ----
__device__ __forceinline__ unsigned f2s(float f) {
    unsigned u = __float_as_uint(f);
    return (u & 0x80000000u) ? ~u : (u | 0x80000000u);
}
__device__ __forceinline__ float s2f(unsigned u) {
    return (u & 0x80000000u) ? __uint_as_float(u ^ 0x80000000u)
                             : __uint_as_float(~u);
}
// Primary-path key: [ f2s(z) : 32 | f2s(r) top 23 bits | y : 9 ].
__device__ __forceinline__ unsigned long long packkey_y(float z, float r,
                                                        unsigned y) {
    return ((unsigned long long)f2s(z) << 32)
         | (unsigned long long)((f2s(r) & ~511u) | y);
}
// Fallback key (R4 scheme): z | full r.
__device__ __forceinline__ unsigned long long packkey(float z, float r) {
    return ((unsigned long long)f2s(z) << 32) | (unsigned long long)f2s(r);
}

// XCD swizzle (locality heuristic ONLY — correctness never depends on it).
__device__ __forceinline__ int swizzle(int g, int swz) {
    return swz ? ((g & 7) * (NB / 8) + (g >> 3)) : g;
}

// ================= primary (atomic-free, histogram-free) path =================

// K1: placement into PRIVATE per-block segments (one 8192-pt flush per block).
// UNCHANGED (R0-proven) for clean attribution.
__global__ __launch_bounds__(1024)
void place_kernel(const v4f* __restrict__ fea, const v2i* __restrict__ xy,
                  unsigned long long* __restrict__ keyA,
                  unsigned* __restrict__ meta, int swz) {
    __shared__ unsigned long long skey[SC];       // 64 KB
    __shared__ unsigned lcnt[LBINS], loff[LBINS]; // 4 KB
    __shared__ unsigned wsum[8];
    int t = threadIdx.x;
    int blk = swizzle(blockIdx.x, swz);
    int start = blk * SC;
    if (t < LBINS) lcnt[t] = 0;
    __syncthreads();

    unsigned long long k[SPT]; unsigned lb[SPT], rk[SPT];
    #pragma unroll
    for (int kk = 0; kk < SPT; ++kk) {
        int p = start + t + kk * PT;
        v2i q = __builtin_nontemporal_load(xy + p);
        v4f ff = __builtin_nontemporal_load(fea + p);
        k[kk]  = packkey_y(ff.z, ff.w, (unsigned)q.y);
        lb[kk] = (unsigned)q.x;
        rk[kk] = atomicAdd(&lcnt[q.x], 1u);
    }
    __syncthreads();

    unsigned c = 0, inc = 0;
    if (t < LBINS) {
        c = lcnt[t];
        inc = c;
        int lane = t & 63;
        #pragma unroll
        for (int off = 1; off < 64; off <<= 1) {
            unsigned o = __shfl_up(inc, off);
            if (lane >= off) inc += o;
        }
        if (lane == 63) wsum[t >> 6] = inc;
    }
    __syncthreads();
    if (t < 8) {
        unsigned v = wsum[t], i2 = v;
        #pragma unroll
        for (int off = 1; off < 8; off <<= 1) {
            unsigned o = __shfl_up(i2, off, 8);
            if (t >= off) i2 += o;
        }
        wsum[t] = i2 - v;
    }
    __syncthreads();
    if (t < LBINS) loff[t] = inc - c + wsum[t >> 6];
    __syncthreads();

    #pragma unroll
    for (int kk = 0; kk < SPT; ++kk)
        skey[loff[lb[kk]] + rk[kk]] = k[kk];
    __syncthreads();

    unsigned long long* dst = keyA + (size_t)blk * SC;
    #pragma unroll
    for (int kk = 0; kk < SPT; ++kk) {
        int s = t + kk * PT;
        dst[s] = skey[s];
    }
    if (t < LBINS)
        meta[(size_t)blk * LBINS + t] = (loff[t] << 16) | lcnt[t];
}

// K2fused v2: cooperative rowreduce + batch min/max + normalize, ONE kernel.
// CONSERVATIVE cooperative config: 256 blocks x 1024 threads = 1 block/CU
// residency requirement (the weakest possible).  Each block owns 8 x-groups
// (32 bins) of one batch.  Per-voxel u64 keys persist in 32 VGPRs; per-voxel
// counts persist in a 32 KB LDS array (keeps VGPR <= 128 so 16 waves/CU fit).
// The unnormalized grid is never written and never re-read.
__global__ __launch_bounds__(1024, 4)
void fused_kernel(const unsigned long long* __restrict__ keyA,
                  const unsigned* __restrict__ meta,
                  float* __restrict__ out,
                  float* __restrict__ partials) {
    __shared__ unsigned long long sk[2048];       // 16 KB (reused per group)
    __shared__ unsigned scnt[2048];               // 8 KB (reused per group)
    __shared__ unsigned short pcnt[8][2048];      // 32 KB persistent counts
    __shared__ float red[16][6];
    __shared__ float pred[16][6];
    int t = threadIdx.x;
    int blk = blockIdx.x;
    int batch = blk >> 4;                         // 16 blocks per batch
    int bb = blk & 15;
    int seg = t >> 5, l = t & 31;                 // 32 segments x 32 lanes
    size_t sidx = (size_t)(batch * 32 + seg);     // bpblk == 32 (gated)

    unsigned long long hk[16];                    // persistent voxel keys
    float n0 = INFINITY, mx0 = -INFINITY, n1 = INFINITY, mx1 = -INFINITY,
          n2 = INFINITY, mx2 = -INFINITY;

    #pragma unroll
    for (int gi = 0; gi < 8; ++gi) {
        int xg = bb * 8 + gi;                     // x-group within batch
        int x0 = xg * XG;
        // zero own slots (prev extraction read only own slots -> no barrier)
        sk[t] = 0; sk[t + 1024] = 0; scnt[t] = 0; scnt[t + 1024] = 0;
        __syncthreads();

        uint4 m = *(const uint4*)(meta + sidx * LBINS + x0);   // 16B-aligned
        unsigned lo0 = m.x >> 16;
        unsigned b1 = m.x & 0xFFFFu;
        unsigned b2 = b1 + (m.y & 0xFFFFu);
        unsigned b3 = b2 + (m.z & 0xFFFFu);
        unsigned tot = b3 + (m.w & 0xFFFFu);
        const unsigned long long* src = keyA + sidx * SC + lo0;
        for (unsigned r = l; r < tot; r += 32) {
            unsigned long long k = src[r];        // contiguous slice
            int bin = (r >= b1) + (r >= b2) + (r >= b3);
            unsigned y = (unsigned)k & 511u;
            atomicMax(&sk[(bin << 9) + y], k);
            atomicAdd(&scnt[(bin << 9) + y], 1u);
        }
        __syncthreads();

        // extract own 2 voxels: key -> register, count -> persistent LDS
        #pragma unroll
        for (int j = 0; j < 2; ++j) {
            int i = t + j * 1024;
            unsigned cv = scnt[i];
            unsigned long long k = sk[i];
            hk[gi * 2 + j] = k;
            pcnt[gi][i] = (unsigned short)(cv > 65535u ? 65535u : cv);
            float h0 = 0.0f, rr = 0.0f;
            if (cv) {
                h0 = s2f((unsigned)(k >> 32));
                rr = s2f((unsigned)k & ~511u);
            }
            float cf = (float)cv;
            n0 = fminf(n0, h0); mx0 = fmaxf(mx0, h0);
            n1 = fminf(n1, rr); mx1 = fmaxf(mx1, rr);
            n2 = fminf(n2, cf); mx2 = fmaxf(mx2, cf);
        }
    }

    // block-level reduce of the 6 accumulators (16 waves)
    #pragma unroll
    for (int off = 32; off; off >>= 1) {
        n0 = fminf(n0, __shfl_down(n0, off));  mx0 = fmaxf(mx0, __shfl_down(mx0, off));
        n1 = fminf(n1, __shfl_down(n1, off));  mx1 = fmaxf(mx1, __shfl_down(mx1, off));
        n2 = fminf(n2, __shfl_down(n2, off));  mx2 = fmaxf(mx2, __shfl_down(mx2, off));
    }
    int lane = t & 63, wave = t >> 6;
    if (lane == 0) {
        red[wave][0] = n0; red[wave][1] = mx0;
        red[wave][2] = n1; red[wave][3] = mx1;
        red[wave][4] = n2; red[wave][5] = mx2;
    }
    __syncthreads();
    if (t < 6) {
        int j = t;
        float v = red[0][j];
        bool isMin = (j & 1) == 0;
        #pragma unroll
        for (int w = 1; w < 16; ++w)
            v = isMin ? fminf(v, red[w][j]) : fmaxf(v, red[w][j]);
        __hip_atomic_store(&partials[(size_t)blk * 6 + j], v,
                           __ATOMIC_RELEASE, __HIP_MEMORY_SCOPE_AGENT);
    }

    cg::this_grid().sync();

    // every block redundantly reduces its batch's 16x6 partials (96 floats)
    if (t < 96) {
        float v = __hip_atomic_load(&partials[(size_t)(batch << 4) * 6 + t],
                                    __ATOMIC_RELAXED, __HIP_MEMORY_SCOPE_AGENT);
        pred[t / 6][t % 6] = v;
    }
    __syncthreads();
    float bn0 = INFINITY, bx0 = -INFINITY, bn1 = INFINITY, bx1 = -INFINITY,
          bn2 = INFINITY, bx2 = -INFINITY;
    #pragma unroll
    for (int w = 0; w < 16; ++w) {
        bn0 = fminf(bn0, pred[w][0]); bx0 = fmaxf(bx0, pred[w][1]);
        bn1 = fminf(bn1, pred[w][2]); bx1 = fmaxf(bx1, pred[w][3]);
        bn2 = fminf(bn2, pred[w][4]); bx2 = fmaxf(bx2, pred[w][5]);
    }
    float i0 = 1.0f / (bx0 - bn0);
    float i1 = 1.0f / (bx1 - bn1);
    float i2 = 1.0f / (bx2 - bn2);

    // normalized single write of the grid (never re-read)
    size_t ob = ((size_t)batch * 3) << 18;
    #pragma unroll
    for (int gi = 0; gi < 8; ++gi) {
        int xg = bb * 8 + gi;
        size_t xoff = (size_t)xg << 11;           // xg * 2048
        #pragma unroll
        for (int j = 0; j < 2; ++j) {
            int i = t + j * 1024;
            int idx = gi * 2 + j;
            unsigned cv = pcnt[gi][i];
            unsigned long long k = hk[idx];
            float h0 = 0.0f, rr = 0.0f;
            if (cv) {
                h0 = s2f((unsigned)(k >> 32));
                rr = s2f((unsigned)k & ~511u);
            }
            float cf = (float)cv;
            __builtin_nontemporal_store((h0 - bn0) * i0, out + ob + xoff + i);
            __builtin_nontemporal_store((rr - bn1) * i1, out + ob + (size_t)GXY + xoff + i);
            __builtin_nontemporal_store((cf - bn2) * i2, out + ob + (size_t)(2 * GXY) + xoff + i);
        }
    }
}

// K2 (fallback tail): rowreduce, R0-proven.
__global__ __launch_bounds__(512)
void rowreduce_kernel(const unsigned long long* __restrict__ keyA,
                      const unsigned* __restrict__ meta,
                      float* __restrict__ out,
                      float* __restrict__ partials,
                      int bpblk) {
    __shared__ unsigned long long sk[XG * 512];   // 16 KB
    __shared__ unsigned scnt[XG * 512];           // 8 KB
    __shared__ float red[8][6];
    int t = threadIdx.x;
    int g = blockIdx.x;
    int batch = g >> 7;
    int xg = g & 127;
    int x0 = xg * XG;
    for (int i = t; i < XG * 512; i += 512) { sk[i] = 0; scnt[i] = 0; }
    __syncthreads();

    int seg = t >> 4, l16 = t & 15;
    size_t sidx = (size_t)(batch * bpblk + seg);
    uint4 m = *(const uint4*)(meta + sidx * LBINS + x0);
    unsigned lo0 = m.x >> 16;
    unsigned b1 = m.x & 0xFFFFu;
    unsigned b2 = b1 + (m.y & 0xFFFFu);
    unsigned b3 = b2 + (m.z & 0xFFFFu);
    unsigned tot = b3 + (m.w & 0xFFFFu);
    const unsigned long long* src = keyA + sidx * SC + lo0;
    for (unsigned r = l16; r < tot; r += 16) {
        unsigned long long k = src[r];
        int bin = (r >= b1) + (r >= b2) + (r >= b3);
        unsigned y = (unsigned)k & 511u;
        atomicMax(&sk[(bin << 9) + y], k);
        atomicAdd(&scnt[(bin << 9) + y], 1u);
    }
    __syncthreads();

    size_t ob = ((size_t)batch * 3) << 18;
    size_t xoff = (size_t)x0 << 9;
    float n0 = INFINITY, mx0 = -INFINITY, n1 = INFINITY, mx1 = -INFINITY,
          n2 = INFINITY, mx2 = -INFINITY;
    for (int i = t; i < XG * 512; i += 512) {
        unsigned cv = scnt[i];
        float h0 = 0.0f, r = 0.0f;
        if (cv) {
            unsigned long long k = sk[i];
            h0 = s2f((unsigned)(k >> 32));
            r  = s2f((unsigned)k & ~511u);
        }
        float cf = (float)cv;
        out[ob + xoff + i] = h0;
        out[ob + (size_t)GXY + xoff + i] = r;
        out[ob + (size_t)(2 * GXY) + xoff + i] = cf;
        n0 = fminf(n0, h0); mx0 = fmaxf(mx0, h0);
        n1 = fminf(n1, r);  mx1 = fmaxf(mx1, r);
        n2 = fminf(n2, cf); mx2 = fmaxf(mx2, cf);
    }
    #pragma unroll
    for (int off = 32; off; off >>= 1) {
        n0 = fminf(n0, __shfl_down(n0, off));  mx0 = fmaxf(mx0, __shfl_down(mx0, off));
        n1 = fminf(n1, __shfl_down(n1, off));  mx1 = fmaxf(mx1, __shfl_down(mx1, off));
        n2 = fminf(n2, __shfl_down(n2, off));  mx2 = fmaxf(mx2, __shfl_down(mx2, off));
    }
    int lane = t & 63, wave = t >> 6;
    if (lane == 0) {
        red[wave][0] = n0; red[wave][1] = mx0;
        red[wave][2] = n1; red[wave][3] = mx1;
        red[wave][4] = n2; red[wave][5] = mx2;
    }
    __syncthreads();
    if (t < 6) {
        int j = t;
        float v = red[0][j];
        bool isMin = (j & 1) == 0;
        #pragma unroll
        for (int w = 1; w < 8; ++w)
            v = isMin ? fminf(v, red[w][j]) : fmaxf(v, red[w][j]);
        partials[(size_t)g * 6 + j] = v;
    }
}

// K3: reduce per-group partials -> mn/mx (fallback tail only).
__global__ void reduce_kernel(const float* __restrict__ partials,
                              float* __restrict__ mn,
                              float* __restrict__ mx,
                              int rows) {
    int b = blockIdx.x / 6;
    int j = blockIdx.x - b * 6;
    bool isMin = (j & 1) == 0;
    float v = isMin ? INFINITY : -INFINITY;
    for (int i = threadIdx.x; i < rows; i += blockDim.x) {
        float p = partials[((size_t)b * rows + i) * 6 + j];
        v = isMin ? fminf(v, p) : fmaxf(v, p);
    }
    #pragma unroll
    for (int off = 32; off; off >>= 1) {
        float o = __shfl_down(v, off);
        v = isMin ? fminf(v, o) : fmaxf(v, o);
    }
    __shared__ float red[4];
    int lane = threadIdx.x & 63, wave = threadIdx.x >> 6;
    if (lane == 0) red[wave] = v;
    __syncthreads();
    if (threadIdx.x == 0) {
        #pragma unroll
        for (int w = 1; w < 4 && w < (int)(blockDim.x >> 6); ++w)
            v = isMin ? fminf(v, red[w]) : fmaxf(v, red[w]);
        int slot = b * 3 + (j >> 1);
        if (isMin) mn[slot] = v; else mx[slot] = v;
    }
}

// K4: in-place (v - mn) / (mx - mn) (fallback tail only).
__global__ void norm_kernel(v4f* __restrict__ out,
                            const float* __restrict__ mn,
                            const float* __restrict__ mx,
                            int total4) {
    int i = blockIdx.x * blockDim.x + threadIdx.x;
    if (i >= total4) return;
    int slot = i >> 16;
    float lo = mn[slot];
    float inv = 1.0f / (mx[slot] - lo);
    v4f v = __builtin_nontemporal_load(out + i);
    v.x = (v.x - lo) * inv;
    v.y = (v.y - lo) * inv;
    v.z = (v.z - lo) * inv;
    v.w = (v.w - lo) * inv;
    __builtin_nontemporal_store(v, out + i);
}

// ================= fallback path (R4 structure) =================
__global__ void scatter_fb(const v4f* __restrict__ fea, const v2i* __restrict__ xy,
                           unsigned long long* __restrict__ keys,
                           unsigned* __restrict__ cnt32, int N, int P) {
    int p = blockIdx.x * blockDim.x + threadIdx.x;
    if (p >= P) return;
    v2i q = __builtin_nontemporal_load(xy + p);
    v4f f = __builtin_nontemporal_load(fea + p);
    int vid = ((p / N) * GXC + q.x) * GYC + q.y;
    atomicMax(&keys[vid], packkey(f.z, f.w));
    atomicAdd(&cnt32[vid >> 2], 1u << ((vid & 3) * 8));
}

__global__ void fill_fb(const unsigned long long* __restrict__ keys,
                        const unsigned char* __restrict__ cntB,
                        float* __restrict__ out, float* __restrict__ partials) {
    int g = blockIdx.x;
    int batch = g / BPB, blkInB = g - batch * BPB;
    int rem = blkInB * 256 + threadIdx.x;
    int s = batch * GXY + rem;
    unsigned c = cntB[s];
    float h0 = 0.0f, r = 0.0f;
    if (c) {
        unsigned long long k = keys[s];
        h0 = s2f((unsigned)(k >> 32));
        r  = s2f((unsigned)(k & 0xFFFFFFFFull));
    }
    float cf = (float)c;
    size_t base = (size_t)batch * 3 * GXY + rem;
    out[base] = h0; out[base + GXY] = r; out[base + 2 * GXY] = cf;
    float n0 = h0, x0 = h0, n1 = r, x1 = r, n2 = cf, x2 = cf;
    #pragma unroll
    for (int off = 32; off; off >>= 1) {
        n0 = fminf(n0, __shfl_down(n0, off)); x0 = fmaxf(x0, __shfl_down(x0, off));
        n1 = fminf(n1, __shfl_down(n1, off)); x1 = fmaxf(x1, __shfl_down(x1, off));
        n2 = fminf(n2, __shfl_down(n2, off)); x2 = fmaxf(x2, __shfl_down(x2, off));
    }
    __shared__ float red[4][6];
    int lane = threadIdx.x & 63, wave = threadIdx.x >> 6;
    if (lane == 0) {
        red[wave][0] = n0; red[wave][1] = x0; red[wave][2] = n1;
        red[wave][3] = x1; red[wave][4] = n2; red[wave][5] = x2;
    }
    __syncthreads();
    if (threadIdx.x < 6) {
        int j = threadIdx.x;
        float v = red[0][j];
        bool isMin = (j & 1) == 0;
        #pragma unroll
        for (int w = 1; w < 4; ++w)
            v = isMin ? fminf(v, red[w][j]) : fmaxf(v, red[w][j]);
        partials[(size_t)(batch * BPB + blkInB) * 6 + j] = v;
    }
}

extern "C" void kernel_launch(void* const* d_in, const int* in_sizes, int n_in,
                              void* d_out, int out_size, void* d_ws, size_t ws_size,
                              hipStream_t stream) {
    const v4f* fea = (const v4f*)d_in[0];   // [B, N, 4] f32
    const v2i* xy  = (const v2i*)d_in[1];   // [B, N, 2] i32

    int P = in_sizes[0] / 4;
    int B = out_size / (3 * GXY);
    int N = (B > 0) ? P / B : 0;
    int S = B * GXY;
    int NBIN = B * GXC;
    int bpblk = (B > 0) ? NB / B : 0;       // place blocks (=segments) per batch

    char* ws = (char*)d_ws;
    unsigned long long* keyA = (unsigned long long*)ws;
    size_t o = (size_t)P * 8;
    unsigned* meta = (unsigned*)(ws + o);   o += (size_t)NB * LBINS * 4;
    float* partials = (float*)(ws + o);     o += (size_t)(NBIN / XG) * 6 * 4;
    float* mn = (float*)(ws + o);           o += (size_t)B * 3 * 4;
    float* mx = (float*)(ws + o);           o += (size_t)B * 3 * 4;
    size_t need = o;

    int swz = (B % 8 == 0) ? 1 : 0;

    // Gate: exact bench shape (B=16, N=262144): bpblk==32 forces B=16, so the
    // fused kernel's hardcoded 16-blocks/batch and 256-block grid are valid.
    bool ok = B > 0 && NB % B == 0 && bpblk == 32 && P == NB * SC
              && N == bpblk * SC && ws_size >= need;

    if (ok) {
        place_kernel<<<NB, PT, 0, stream>>>(fea, xy, keyA, meta, swz);
        float* outp = (float*)d_out;
        void* args[] = {(void*)&keyA, (void*)&meta, (void*)&outp, (void*)&partials};
        // Conservative cooperative grid: 256 blocks = 1 block/CU residency.
        hipError_t ce = hipLaunchCooperativeKernel(
            reinterpret_cast<void*>(fused_kernel), dim3(256), dim3(1024),
            args, 0, stream);
        if (ce != hipSuccess) {
            // R0-proven 3-kernel tail; numerics byte-identical to R0.
            rowreduce_kernel<<<NBIN / XG, 512, 0, stream>>>(keyA, meta,
                                                            (float*)d_out,
                                                            partials, bpblk);
            reduce_kernel<<<B * 6, 256, 0, stream>>>(partials, mn, mx, GXC / XG);
            norm_kernel<<<(out_size / 4 + 255) / 256, 256, 0, stream>>>(
                (v4f*)d_out, mn, mx, out_size / 4);
        }
    } else {
        float* mn_f = (float*)ws;
        float* mx_f = (float*)(ws + 256);
        float* part_f = (float*)(ws + 512);
        size_t hdr = 512 + (size_t)B * BPB * 6 * 4;
        unsigned long long* keys = (unsigned long long*)(ws + hdr);
        unsigned char* cntB = (unsigned char*)(ws + hdr + (size_t)S * 8);
        (void)hipMemsetAsync(keys, 0x00, (size_t)S * 9, stream);
        scatter_fb<<<(P + 255) / 256, 256, 0, stream>>>(fea, xy, keys,
                                                        (unsigned*)cntB, N, P);
        fill_fb<<<S / 256, 256, 0, stream>>>(keys, cntB, (float*)d_out, part_f);
        reduce_kernel<<<B * 6, 256, 0, stream>>>(part_f, mn_f, mx_f, BPB);
        norm_kernel<<<(out_size / 4 + 255) / 256, 256, 0, stream>>>((v4f*)d_out,
                                                                    mn_f, mx_f,
                                                                    out_size / 4);
    }
}

// Round 3
// 177.703 us; speedup vs baseline: 1.1706x; 1.1706x over previous
//
#include <hip/hip_runtime.h>
#include <stdint.h>

#define GXC 512
#define GYC 512
#define GXY (GXC * GYC)     // 262144 voxels per batch
#define NB  512             // place blocks
#define SC  8192            // points per block = one flush (FPB=1)
#define PT  1024            // place threads per block
#define SPT (SC / PT)       // staged points per thread = 8
#define LBINS 512           // local bins = GXC (chunk stays inside one batch)
#define XG  4               // bins per rowreduce block
#define BPB (GXY / 256)     // fallback fill blocks per batch = 1024

typedef float v4f __attribute__((ext_vector_type(4)));
typedef int   v2i __attribute__((ext_vector_type(2)));
typedef unsigned long long v2u64 __attribute__((ext_vector_type(2)));

// ---- monotone float <-> sortable-uint mapping ----
__device__ __forceinline__ unsigned f2s(float f) {
    unsigned u = __float_as_uint(f);
    return (u & 0x80000000u) ? ~u : (u | 0x80000000u);
}
__device__ __forceinline__ float s2f(unsigned u) {
    return (u & 0x80000000u) ? __uint_as_float(u ^ 0x80000000u)
                             : __uint_as_float(~u);
}
// Primary-path key: [ f2s(z) : 32 | f2s(r) top 23 bits | y : 9 ].
__device__ __forceinline__ unsigned long long packkey_y(float z, float r,
                                                        unsigned y) {
    return ((unsigned long long)f2s(z) << 32)
         | (unsigned long long)((f2s(r) & ~511u) | y);
}
// Fallback key (R4 scheme): z | full r.
__device__ __forceinline__ unsigned long long packkey(float z, float r) {
    return ((unsigned long long)f2s(z) << 32) | (unsigned long long)f2s(r);
}

// XCD swizzle (locality heuristic ONLY — correctness never depends on it).
__device__ __forceinline__ int swizzle(int g, int swz) {
    return swz ? ((g & 7) * (NB / 8) + (g >> 3)) : g;
}

// ================= primary (atomic-free, histogram-free) path =================

// K1: placement into PRIVATE per-block segments (one 8192-pt flush per block).
// R3: + block 0 inits the u32 min/max accumulators (replaces K3's buffers;
// visible to K2 via stream-ordered dispatch); flush widened to 16 B.
__global__ __launch_bounds__(1024)
void place_kernel(const v4f* __restrict__ fea, const v2i* __restrict__ xy,
                  unsigned long long* __restrict__ keyA,
                  unsigned* __restrict__ meta,
                  unsigned* __restrict__ mnu, unsigned* __restrict__ mxu,
                  int swz) {
    __shared__ __align__(16) unsigned long long skey[SC];  // 64 KB
    __shared__ unsigned lcnt[LBINS], loff[LBINS];          // 4 KB
    __shared__ unsigned wsum[8];
    int t = threadIdx.x;
    int blk = swizzle(blockIdx.x, swz);
    int start = blk * SC;
    if (t < LBINS) lcnt[t] = 0;
    // init global min/max accumulators (gate guarantees B=16 -> 48 channels).
    // mx init 0x0 < f2s(any finite); mn init 0xFFFFFFFF > f2s(any finite).
    if (blockIdx.x == 0 && t < 96) {
        if (t < 48) mxu[t] = 0u; else mnu[t - 48] = 0xFFFFFFFFu;
    }
    __syncthreads();

    // read + rank (SPT slots -> registers); P % (NB*SC) == 0 -> no bounds check
    unsigned long long k[SPT]; unsigned lb[SPT], rk[SPT];
    #pragma unroll
    for (int kk = 0; kk < SPT; ++kk) {
        int p = start + t + kk * PT;
        v2i q = __builtin_nontemporal_load(xy + p);
        v4f ff = __builtin_nontemporal_load(fea + p);
        k[kk]  = packkey_y(ff.z, ff.w, (unsigned)q.y);
        lb[kk] = (unsigned)q.x;
        rk[kk] = atomicAdd(&lcnt[q.x], 1u);
    }
    __syncthreads();

    // exclusive scan of lcnt[512] using first 512 threads (8 waves)
    unsigned c = 0, inc = 0;
    if (t < LBINS) {
        c = lcnt[t];
        inc = c;
        int lane = t & 63;
        #pragma unroll
        for (int off = 1; off < 64; off <<= 1) {
            unsigned o = __shfl_up(inc, off);
            if (lane >= off) inc += o;
        }
        if (lane == 63) wsum[t >> 6] = inc;
    }
    __syncthreads();
    if (t < 8) {
        unsigned v = wsum[t], i2 = v;
        #pragma unroll
        for (int off = 1; off < 8; off <<= 1) {
            unsigned o = __shfl_up(i2, off, 8);
            if (t >= off) i2 += o;
        }
        wsum[t] = i2 - v;                         // exclusive wave offsets
    }
    __syncthreads();
    if (t < LBINS) loff[t] = inc - c + wsum[t >> 6];
    __syncthreads();

    // stage bin-grouped
    #pragma unroll
    for (int kk = 0; kk < SPT; ++kk)
        skey[loff[lb[kk]] + rk[kk]] = k[kk];
    __syncthreads();

    // flush: sequential coalesced 16 B stores (b128 LDS reads, conflict-free)
    v2u64* dst2 = (v2u64*)(keyA + (size_t)blk * SC);
    const v2u64* src2 = (const v2u64*)skey;
    #pragma unroll
    for (int kk = 0; kk < SPT / 2; ++kk) {
        int s = t + kk * PT;
        dst2[s] = src2[s];
    }
    if (t < LBINS)
        meta[(size_t)blk * LBINS + t] = (loff[t] << 16) | lcnt[t];
}

// K2: one block per (batch, 4 consecutive x bins); contiguous per-segment
// slices (~64 keys = 512 B) gathered by 16 lanes each; LDS max/count over
// 4x512 y-slots; fused fill with 8 KB-contiguous channel writes.
// R3: per-block min/max published via device-scope atomicMin/Max on
// f2s-mapped u32 (exact, order-free) -> K3 eliminated.
__global__ __launch_bounds__(512)
void rowreduce_kernel(const unsigned long long* __restrict__ keyA,
                      const unsigned* __restrict__ meta,
                      float* __restrict__ out,
                      unsigned* __restrict__ mnu, unsigned* __restrict__ mxu,
                      int bpblk) {
    __shared__ unsigned long long sk[XG * 512];   // 16 KB
    __shared__ unsigned scnt[XG * 512];           // 8 KB
    __shared__ float red[8][6];
    int t = threadIdx.x;
    int g = blockIdx.x;
    int batch = g >> 7;                           // 128 x-groups per batch
    int xg = g & 127;
    int x0 = xg * XG;
    for (int i = t; i < XG * 512; i += 512) { sk[i] = 0; scnt[i] = 0; }
    __syncthreads();

    // 512 threads / 32 segments = 16 lanes per segment
    int seg = t >> 4, l16 = t & 15;
    size_t sidx = (size_t)(batch * bpblk + seg);  // FPB == 1
    uint4 m = *(const uint4*)(meta + sidx * LBINS + x0);   // 16B-aligned
    unsigned lo0 = m.x >> 16;
    unsigned b1 = m.x & 0xFFFFu;
    unsigned b2 = b1 + (m.y & 0xFFFFu);
    unsigned b3 = b2 + (m.z & 0xFFFFu);
    unsigned tot = b3 + (m.w & 0xFFFFu);
    const unsigned long long* src = keyA + sidx * SC + lo0;
    for (unsigned r = l16; r < tot; r += 16) {
        unsigned long long k = src[r];            // contiguous slice
        int bin = (r >= b1) + (r >= b2) + (r >= b3);
        unsigned y = (unsigned)k & 511u;
        atomicMax(&sk[(bin << 9) + y], k);
        atomicAdd(&scnt[(bin << 9) + y], 1u);
    }
    __syncthreads();

    size_t ob = ((size_t)batch * 3) << 18;
    size_t xoff = (size_t)x0 << 9;
    float n0 = INFINITY, mx0 = -INFINITY, n1 = INFINITY, mx1 = -INFINITY,
          n2 = INFINITY, mx2 = -INFINITY;
    for (int i = t; i < XG * 512; i += 512) {     // i = (bin<<9)+y, row-major
        unsigned cv = scnt[i];
        float h0 = 0.0f, r = 0.0f;
        if (cv) {
            unsigned long long k = sk[i];
            h0 = s2f((unsigned)(k >> 32));
            r  = s2f((unsigned)k & ~511u);
        }
        float cf = (float)cv;
        out[ob + xoff + i] = h0;                  // plain stores -> L3 for K4
        out[ob + (size_t)GXY + xoff + i] = r;
        out[ob + (size_t)(2 * GXY) + xoff + i] = cf;
        n0 = fminf(n0, h0); mx0 = fmaxf(mx0, h0);
        n1 = fminf(n1, r);  mx1 = fmaxf(mx1, r);
        n2 = fminf(n2, cf); mx2 = fmaxf(mx2, cf);
    }
    #pragma unroll
    for (int off = 32; off; off >>= 1) {
        n0 = fminf(n0, __shfl_down(n0, off));  mx0 = fmaxf(mx0, __shfl_down(mx0, off));
        n1 = fminf(n1, __shfl_down(n1, off));  mx1 = fmaxf(mx1, __shfl_down(mx1, off));
        n2 = fminf(n2, __shfl_down(n2, off));  mx2 = fmaxf(mx2, __shfl_down(mx2, off));
    }
    int lane = t & 63, wave = t >> 6;
    if (lane == 0) {
        red[wave][0] = n0; red[wave][1] = mx0;
        red[wave][2] = n1; red[wave][3] = mx1;
        red[wave][4] = n2; red[wave][5] = mx2;
    }
    __syncthreads();
    if (t < 6) {
        int j = t;
        float v = red[0][j];
        bool isMin = (j & 1) == 0;
        #pragma unroll
        for (int w = 1; w < 8; ++w)
            v = isMin ? fminf(v, red[w][j]) : fmaxf(v, red[w][j]);
        int ch = batch * 3 + (j >> 1);
        unsigned uv = f2s(v);
        if (isMin) atomicMin(&mnu[ch], uv);       // device-scope, 6/block
        else       atomicMax(&mxu[ch], uv);
    }
}

// K4 (primary): in-place (v - mn) / (mx - mn) from u32-mapped mn/mx.
// Plain load (out is L3-resident from K2's plain stores); nt store (final).
__global__ void norm_kernel(v4f* __restrict__ out,
                            const unsigned* __restrict__ mnu,
                            const unsigned* __restrict__ mxu,
                            int total4) {
    int i = blockIdx.x * blockDim.x + threadIdx.x;
    if (i >= total4) return;
    int slot = i >> 16;
    float lo = s2f(mnu[slot]);
    float inv = 1.0f / (s2f(mxu[slot]) - lo);
    v4f v = out[i];
    v.x = (v.x - lo) * inv;
    v.y = (v.y - lo) * inv;
    v.z = (v.z - lo) * inv;
    v.w = (v.w - lo) * inv;
    __builtin_nontemporal_store(v, out + i);
}

// ================= fallback-path kernels (R4 structure, proven) =================
__global__ void reduce_kernel(const float* __restrict__ partials,
                              float* __restrict__ mn,
                              float* __restrict__ mx,
                              int rows) {
    int b = blockIdx.x / 6;
    int j = blockIdx.x - b * 6;
    bool isMin = (j & 1) == 0;
    float v = isMin ? INFINITY : -INFINITY;
    for (int i = threadIdx.x; i < rows; i += blockDim.x) {
        float p = partials[((size_t)b * rows + i) * 6 + j];
        v = isMin ? fminf(v, p) : fmaxf(v, p);
    }
    #pragma unroll
    for (int off = 32; off; off >>= 1) {
        float o = __shfl_down(v, off);
        v = isMin ? fminf(v, o) : fmaxf(v, o);
    }
    __shared__ float red[4];
    int lane = threadIdx.x & 63, wave = threadIdx.x >> 6;
    if (lane == 0) red[wave] = v;
    __syncthreads();
    if (threadIdx.x == 0) {
        #pragma unroll
        for (int w = 1; w < 4 && w < (int)(blockDim.x >> 6); ++w)
            v = isMin ? fminf(v, red[w]) : fmaxf(v, red[w]);
        int slot = b * 3 + (j >> 1);
        if (isMin) mn[slot] = v; else mx[slot] = v;
    }
}

__global__ void norm_f32_kernel(v4f* __restrict__ out,
                                const float* __restrict__ mn,
                                const float* __restrict__ mx,
                                int total4) {
    int i = blockIdx.x * blockDim.x + threadIdx.x;
    if (i >= total4) return;
    int slot = i >> 16;
    float lo = mn[slot];
    float inv = 1.0f / (mx[slot] - lo);
    v4f v = __builtin_nontemporal_load(out + i);
    v.x = (v.x - lo) * inv;
    v.y = (v.y - lo) * inv;
    v.z = (v.z - lo) * inv;
    v.w = (v.w - lo) * inv;
    __builtin_nontemporal_store(v, out + i);
}

__global__ void scatter_fb(const v4f* __restrict__ fea, const v2i* __restrict__ xy,
                           unsigned long long* __restrict__ keys,
                           unsigned* __restrict__ cnt32, int N, int P) {
    int p = blockIdx.x * blockDim.x + threadIdx.x;
    if (p >= P) return;
    v2i q = __builtin_nontemporal_load(xy + p);
    v4f f = __builtin_nontemporal_load(fea + p);
    int vid = ((p / N) * GXC + q.x) * GYC + q.y;
    atomicMax(&keys[vid], packkey(f.z, f.w));
    atomicAdd(&cnt32[vid >> 2], 1u << ((vid & 3) * 8));
}

__global__ void fill_fb(const unsigned long long* __restrict__ keys,
                        const unsigned char* __restrict__ cntB,
                        float* __restrict__ out, float* __restrict__ partials) {
    int g = blockIdx.x;
    int batch = g / BPB, blkInB = g - batch * BPB;
    int rem = blkInB * 256 + threadIdx.x;
    int s = batch * GXY + rem;
    unsigned c = cntB[s];
    float h0 = 0.0f, r = 0.0f;
    if (c) {
        unsigned long long k = keys[s];
        h0 = s2f((unsigned)(k >> 32));
        r  = s2f((unsigned)(k & 0xFFFFFFFFull));
    }
    float cf = (float)c;
    size_t base = (size_t)batch * 3 * GXY + rem;
    out[base] = h0; out[base + GXY] = r; out[base + 2 * GXY] = cf;
    float n0 = h0, x0 = h0, n1 = r, x1 = r, n2 = cf, x2 = cf;
    #pragma unroll
    for (int off = 32; off; off >>= 1) {
        n0 = fminf(n0, __shfl_down(n0, off)); x0 = fmaxf(x0, __shfl_down(x0, off));
        n1 = fminf(n1, __shfl_down(n1, off)); x1 = fmaxf(x1, __shfl_down(x1, off));
        n2 = fminf(n2, __shfl_down(n2, off)); x2 = fmaxf(x2, __shfl_down(x2, off));
    }
    __shared__ float red[4][6];
    int lane = threadIdx.x & 63, wave = threadIdx.x >> 6;
    if (lane == 0) {
        red[wave][0] = n0; red[wave][1] = x0; red[wave][2] = n1;
        red[wave][3] = x1; red[wave][4] = n2; red[wave][5] = x2;
    }
    __syncthreads();
    if (threadIdx.x < 6) {
        int j = threadIdx.x;
        float v = red[0][j];
        bool isMin = (j & 1) == 0;
        #pragma unroll
        for (int w = 1; w < 4; ++w)
            v = isMin ? fminf(v, red[w][j]) : fmaxf(v, red[w][j]);
        partials[(size_t)(batch * BPB + blkInB) * 6 + j] = v;
    }
}

extern "C" void kernel_launch(void* const* d_in, const int* in_sizes, int n_in,
                              void* d_out, int out_size, void* d_ws, size_t ws_size,
                              hipStream_t stream) {
    const v4f* fea = (const v4f*)d_in[0];   // [B, N, 4] f32
    const v2i* xy  = (const v2i*)d_in[1];   // [B, N, 2] i32

    int P = in_sizes[0] / 4;
    int B = out_size / (3 * GXY);
    int N = (B > 0) ? P / B : 0;
    int S = B * GXY;
    int bpblk = (B > 0) ? NB / B : 0;       // place blocks (=segments) per batch

    char* ws = (char*)d_ws;
    unsigned long long* keyA = (unsigned long long*)ws;
    size_t o = (size_t)P * 8;
    unsigned* meta = (unsigned*)(ws + o);   o += (size_t)NB * LBINS * 4;
    unsigned* mnu = (unsigned*)(ws + o);    o += (size_t)B * 3 * 4;
    unsigned* mxu = (unsigned*)(ws + o);    o += (size_t)B * 3 * 4;
    size_t need = o;

    int swz = (B % 8 == 0) ? 1 : 0;

    // Gate: exact bench shape (B=16, N=262144): one 8192-pt flush per block,
    // 32 segments per batch, 512-bin batches (bpblk==32 with NB=512 -> B=16).
    bool ok = B > 0 && NB % B == 0 && bpblk == 32 && P == NB * SC
              && N == bpblk * SC && ws_size >= need;

    if (ok) {
        // every ws byte used is fully overwritten each call -> no memsets
        // despite 0xAA re-poison (mnu/mxu inited by K1 block 0, consumed by
        // K2 atomics after the stream-ordered dispatch boundary).
        place_kernel<<<NB, PT, 0, stream>>>(fea, xy, keyA, meta, mnu, mxu, swz);
        rowreduce_kernel<<<(B * GXC) / XG, 512, 0, stream>>>(keyA, meta,
                                                             (float*)d_out,
                                                             mnu, mxu, bpblk);
        norm_kernel<<<(out_size / 4 + 255) / 256, 256, 0, stream>>>(
            (v4f*)d_out, mnu, mxu, out_size / 4);
    } else {
        float* mn_f = (float*)ws;
        float* mx_f = (float*)(ws + 256);
        float* part_f = (float*)(ws + 512);
        size_t hdr = 512 + (size_t)B * BPB * 6 * 4;
        unsigned long long* keys = (unsigned long long*)(ws + hdr);
        unsigned char* cntB = (unsigned char*)(ws + hdr + (size_t)S * 8);
        (void)hipMemsetAsync(keys, 0x00, (size_t)S * 9, stream);
        scatter_fb<<<(P + 255) / 256, 256, 0, stream>>>(fea, xy, keys,
                                                        (unsigned*)cntB, N, P);
        fill_fb<<<S / 256, 256, 0, stream>>>(keys, cntB, (float*)d_out, part_f);
        reduce_kernel<<<B * 6, 256, 0, stream>>>(part_f, mn_f, mx_f, BPB);
        norm_f32_kernel<<<(out_size / 4 + 255) / 256, 256, 0, stream>>>(
            (v4f*)d_out, mn_f, mx_f, out_size / 4);
    }
}

// Round 4
// 167.349 us; speedup vs baseline: 1.2431x; 1.0619x over previous
//
#include <hip/hip_runtime.h>
#include <stdint.h>

#define GXC 512
#define GYC 512
#define GXY (GXC * GYC)     // 262144 voxels per batch
#define NB  512             // place blocks
#define SC  8192            // points per block = one flush (FPB=1)
#define PT  1024            // place threads per block
#define SPT (SC / PT)       // staged points per thread = 8
#define LBINS 512           // local bins = GXC (chunk stays inside one batch)
#define XG  4               // bins per rowreduce block
#define BPB (GXY / 256)     // fallback fill blocks per batch = 1024

typedef float v4f __attribute__((ext_vector_type(4)));
typedef int   v2i __attribute__((ext_vector_type(2)));

// ---- monotone float <-> sortable-uint mapping ----
__device__ __forceinline__ unsigned f2s(float f) {
    unsigned u = __float_as_uint(f);
    return (u & 0x80000000u) ? ~u : (u | 0x80000000u);
}
__device__ __forceinline__ float s2f(unsigned u) {
    return (u & 0x80000000u) ? __uint_as_float(u ^ 0x80000000u)
                             : __uint_as_float(~u);
}
// Primary-path key: [ f2s(z) : 32 | f2s(r) top 23 bits | y : 9 ].
__device__ __forceinline__ unsigned long long packkey_y(float z, float r,
                                                        unsigned y) {
    return ((unsigned long long)f2s(z) << 32)
         | (unsigned long long)((f2s(r) & ~511u) | y);
}
// Fallback key (R4 scheme): z | full r.
__device__ __forceinline__ unsigned long long packkey(float z, float r) {
    return ((unsigned long long)f2s(z) << 32) | (unsigned long long)f2s(r);
}

// XCD swizzle (locality heuristic ONLY — correctness never depends on it).
__device__ __forceinline__ int swizzle(int g, int swz) {
    return swz ? ((g & 7) * (NB / 8) + (g >> 3)) : g;
}

// ================= primary (atomic-free, histogram-free) path =================

// K1: placement into PRIVATE per-block segments (one 8192-pt flush per block —
// SC doubled from R9: half the barriers per point). Stage bin-grouped in LDS,
// stream out perfectly sequential; metadata (loff<<16)|cnt in ONE u32 array.
__global__ __launch_bounds__(1024)
void place_kernel(const v4f* __restrict__ fea, const v2i* __restrict__ xy,
                  unsigned long long* __restrict__ keyA,
                  unsigned* __restrict__ meta, int swz) {
    __shared__ unsigned long long skey[SC];       // 64 KB
    __shared__ unsigned lcnt[LBINS], loff[LBINS]; // 4 KB
    __shared__ unsigned wsum[8];
    int t = threadIdx.x;
    int blk = swizzle(blockIdx.x, swz);
    int start = blk * SC;
    if (t < LBINS) lcnt[t] = 0;
    __syncthreads();

    // read + rank (SPT slots -> registers); P % (NB*SC) == 0 -> no bounds check
    unsigned long long k[SPT]; unsigned lb[SPT], rk[SPT];
    #pragma unroll
    for (int kk = 0; kk < SPT; ++kk) {
        int p = start + t + kk * PT;
        v2i q = __builtin_nontemporal_load(xy + p);
        v4f ff = __builtin_nontemporal_load(fea + p);
        k[kk]  = packkey_y(ff.z, ff.w, (unsigned)q.y);
        lb[kk] = (unsigned)q.x;
        rk[kk] = atomicAdd(&lcnt[q.x], 1u);
    }
    __syncthreads();

    // exclusive scan of lcnt[512] using first 512 threads (8 waves)
    unsigned c = 0, inc = 0;
    if (t < LBINS) {
        c = lcnt[t];
        inc = c;
        int lane = t & 63;
        #pragma unroll
        for (int off = 1; off < 64; off <<= 1) {
            unsigned o = __shfl_up(inc, off);
            if (lane >= off) inc += o;
        }
        if (lane == 63) wsum[t >> 6] = inc;
    }
    __syncthreads();
    if (t < 8) {
        unsigned v = wsum[t], i2 = v;
        #pragma unroll
        for (int off = 1; off < 8; off <<= 1) {
            unsigned o = __shfl_up(i2, off, 8);
            if (t >= off) i2 += o;
        }
        wsum[t] = i2 - v;                         // exclusive wave offsets
    }
    __syncthreads();
    if (t < LBINS) loff[t] = inc - c + wsum[t >> 6];
    __syncthreads();

    // stage bin-grouped
    #pragma unroll
    for (int kk = 0; kk < SPT; ++kk)
        skey[loff[lb[kk]] + rk[kk]] = k[kk];
    __syncthreads();

    // flush: sequential coalesced stores + packed metadata
    unsigned long long* dst = keyA + (size_t)blk * SC;
    #pragma unroll
    for (int kk = 0; kk < SPT; ++kk) {
        int s = t + kk * PT;
        dst[s] = skey[s];
    }
    if (t < LBINS)
        meta[(size_t)blk * LBINS + t] = (loff[t] << 16) | lcnt[t];
}

// K2: one block per (batch, 4 consecutive x bins): bins are x-ordered within
// each segment, so the 4 bins form ONE CONTIGUOUS slice (~64 keys = 512 B) per
// segment — coalesced gather. uint4 metadata load covers all 4 bins. LDS
// max/count over 4x512 y-slots, fused fill with 8 KB-contiguous channel
// writes + min/max partials via plain stores.
__global__ __launch_bounds__(512)
void rowreduce_kernel(const unsigned long long* __restrict__ keyA,
                      const unsigned* __restrict__ meta,
                      float* __restrict__ out,
                      float* __restrict__ partials,
                      int bpblk) {
    __shared__ unsigned long long sk[XG * 512];   // 16 KB
    __shared__ unsigned scnt[XG * 512];           // 8 KB
    __shared__ float red[8][6];
    int t = threadIdx.x;
    int g = blockIdx.x;
    int batch = g >> 7;                           // 128 x-groups per batch
    int xg = g & 127;
    int x0 = xg * XG;
    for (int i = t; i < XG * 512; i += 512) { sk[i] = 0; scnt[i] = 0; }
    __syncthreads();

    // 512 threads / 32 segments = 16 lanes per segment
    int seg = t >> 4, l16 = t & 15;
    size_t sidx = (size_t)(batch * bpblk + seg);  // FPB == 1
    uint4 m = *(const uint4*)(meta + sidx * LBINS + x0);   // 16B-aligned
    unsigned lo0 = m.x >> 16;
    unsigned b1 = m.x & 0xFFFFu;
    unsigned b2 = b1 + (m.y & 0xFFFFu);
    unsigned b3 = b2 + (m.z & 0xFFFFu);
    unsigned tot = b3 + (m.w & 0xFFFFu);
    const unsigned long long* src = keyA + sidx * SC + lo0;
    for (unsigned r = l16; r < tot; r += 16) {
        unsigned long long k = src[r];            // contiguous slice
        int bin = (r >= b1) + (r >= b2) + (r >= b3);
        unsigned y = (unsigned)k & 511u;
        atomicMax(&sk[(bin << 9) + y], k);
        atomicAdd(&scnt[(bin << 9) + y], 1u);
    }
    __syncthreads();

    size_t ob = ((size_t)batch * 3) << 18;
    size_t xoff = (size_t)x0 << 9;
    float n0 = INFINITY, mx0 = -INFINITY, n1 = INFINITY, mx1 = -INFINITY,
          n2 = INFINITY, mx2 = -INFINITY;
    for (int i = t; i < XG * 512; i += 512) {     // i = (bin<<9)+y, row-major
        unsigned cv = scnt[i];
        float h0 = 0.0f, r = 0.0f;
        if (cv) {
            unsigned long long k = sk[i];
            h0 = s2f((unsigned)(k >> 32));
            r  = s2f((unsigned)k & ~511u);
        }
        float cf = (float)cv;
        out[ob + xoff + i] = h0;
        out[ob + (size_t)GXY + xoff + i] = r;
        out[ob + (size_t)(2 * GXY) + xoff + i] = cf;
        n0 = fminf(n0, h0); mx0 = fmaxf(mx0, h0);
        n1 = fminf(n1, r);  mx1 = fmaxf(mx1, r);
        n2 = fminf(n2, cf); mx2 = fmaxf(mx2, cf);
    }
    #pragma unroll
    for (int off = 32; off; off >>= 1) {
        n0 = fminf(n0, __shfl_down(n0, off));  mx0 = fmaxf(mx0, __shfl_down(mx0, off));
        n1 = fminf(n1, __shfl_down(n1, off));  mx1 = fmaxf(mx1, __shfl_down(mx1, off));
        n2 = fminf(n2, __shfl_down(n2, off));  mx2 = fmaxf(mx2, __shfl_down(mx2, off));
    }
    int lane = t & 63, wave = t >> 6;
    if (lane == 0) {
        red[wave][0] = n0; red[wave][1] = mx0;
        red[wave][2] = n1; red[wave][3] = mx1;
        red[wave][4] = n2; red[wave][5] = mx2;
    }
    __syncthreads();
    if (t < 6) {
        int j = t;
        float v = red[0][j];
        bool isMin = (j & 1) == 0;
        #pragma unroll
        for (int w = 1; w < 8; ++w)
            v = isMin ? fminf(v, red[w][j]) : fmaxf(v, red[w][j]);
        partials[(size_t)g * 6 + j] = v;          // plain store, no contention
    }
}

// K3: reduce per-group partials -> mn/mx (single writer).
__global__ void reduce_kernel(const float* __restrict__ partials,
                              float* __restrict__ mn,
                              float* __restrict__ mx,
                              int rows) {
    int b = blockIdx.x / 6;
    int j = blockIdx.x - b * 6;
    bool isMin = (j & 1) == 0;
    float v = isMin ? INFINITY : -INFINITY;
    for (int i = threadIdx.x; i < rows; i += blockDim.x) {
        float p = partials[((size_t)b * rows + i) * 6 + j];
        v = isMin ? fminf(v, p) : fmaxf(v, p);
    }
    #pragma unroll
    for (int off = 32; off; off >>= 1) {
        float o = __shfl_down(v, off);
        v = isMin ? fminf(v, o) : fmaxf(v, o);
    }
    __shared__ float red[4];
    int lane = threadIdx.x & 63, wave = threadIdx.x >> 6;
    if (lane == 0) red[wave] = v;
    __syncthreads();
    if (threadIdx.x == 0) {
        #pragma unroll
        for (int w = 1; w < 4 && w < (int)(blockDim.x >> 6); ++w)
            v = isMin ? fminf(v, red[w]) : fmaxf(v, red[w]);
        int slot = b * 3 + (j >> 1);
        if (isMin) mn[slot] = v; else mx[slot] = v;
    }
}

// K4: in-place (v - mn) / (mx - mn), ext-vector float4 + nontemporal (out is
// streamed once each way, never re-read).
__global__ void norm_kernel(v4f* __restrict__ out,
                            const float* __restrict__ mn,
                            const float* __restrict__ mx,
                            int total4) {
    int i = blockIdx.x * blockDim.x + threadIdx.x;
    if (i >= total4) return;
    int slot = i >> 16;
    float lo = mn[slot];
    float inv = 1.0f / (mx[slot] - lo);
    v4f v = __builtin_nontemporal_load(out + i);
    v.x = (v.x - lo) * inv;
    v.y = (v.y - lo) * inv;
    v.z = (v.z - lo) * inv;
    v.w = (v.w - lo) * inv;
    __builtin_nontemporal_store(v, out + i);
}

// ================= fallback path (R4 structure) =================
__global__ void scatter_fb(const v4f* __restrict__ fea, const v2i* __restrict__ xy,
                           unsigned long long* __restrict__ keys,
                           unsigned* __restrict__ cnt32, int N, int P) {
    int p = blockIdx.x * blockDim.x + threadIdx.x;
    if (p >= P) return;
    v2i q = __builtin_nontemporal_load(xy + p);
    v4f f = __builtin_nontemporal_load(fea + p);
    int vid = ((p / N) * GXC + q.x) * GYC + q.y;
    atomicMax(&keys[vid], packkey(f.z, f.w));
    atomicAdd(&cnt32[vid >> 2], 1u << ((vid & 3) * 8));
}

__global__ void fill_fb(const unsigned long long* __restrict__ keys,
                        const unsigned char* __restrict__ cntB,
                        float* __restrict__ out, float* __restrict__ partials) {
    int g = blockIdx.x;
    int batch = g / BPB, blkInB = g - batch * BPB;
    int rem = blkInB * 256 + threadIdx.x;
    int s = batch * GXY + rem;
    unsigned c = cntB[s];
    float h0 = 0.0f, r = 0.0f;
    if (c) {
        unsigned long long k = keys[s];
        h0 = s2f((unsigned)(k >> 32));
        r  = s2f((unsigned)(k & 0xFFFFFFFFull));
    }
    float cf = (float)c;
    size_t base = (size_t)batch * 3 * GXY + rem;
    out[base] = h0; out[base + GXY] = r; out[base + 2 * GXY] = cf;
    float n0 = h0, x0 = h0, n1 = r, x1 = r, n2 = cf, x2 = cf;
    #pragma unroll
    for (int off = 32; off; off >>= 1) {
        n0 = fminf(n0, __shfl_down(n0, off)); x0 = fmaxf(x0, __shfl_down(x0, off));
        n1 = fminf(n1, __shfl_down(n1, off)); x1 = fmaxf(x1, __shfl_down(x1, off));
        n2 = fminf(n2, __shfl_down(n2, off)); x2 = fmaxf(x2, __shfl_down(x2, off));
    }
    __shared__ float red[4][6];
    int lane = threadIdx.x & 63, wave = threadIdx.x >> 6;
    if (lane == 0) {
        red[wave][0] = n0; red[wave][1] = x0; red[wave][2] = n1;
        red[wave][3] = x1; red[wave][4] = n2; red[wave][5] = x2;
    }
    __syncthreads();
    if (threadIdx.x < 6) {
        int j = threadIdx.x;
        float v = red[0][j];
        bool isMin = (j & 1) == 0;
        #pragma unroll
        for (int w = 1; w < 4; ++w)
            v = isMin ? fminf(v, red[w][j]) : fmaxf(v, red[w][j]);
        partials[(size_t)(batch * BPB + blkInB) * 6 + j] = v;
    }
}

extern "C" void kernel_launch(void* const* d_in, const int* in_sizes, int n_in,
                              void* d_out, int out_size, void* d_ws, size_t ws_size,
                              hipStream_t stream) {
    const v4f* fea = (const v4f*)d_in[0];   // [B, N, 4] f32
    const v2i* xy  = (const v2i*)d_in[1];   // [B, N, 2] i32

    int P = in_sizes[0] / 4;
    int B = out_size / (3 * GXY);
    int N = (B > 0) ? P / B : 0;
    int S = B * GXY;
    int NBIN = B * GXC;
    int bpblk = (B > 0) ? NB / B : 0;       // place blocks (=segments) per batch

    char* ws = (char*)d_ws;
    unsigned long long* keyA = (unsigned long long*)ws;
    size_t o = (size_t)P * 8;
    unsigned* meta = (unsigned*)(ws + o);   o += (size_t)NB * LBINS * 4;
    float* partials = (float*)(ws + o);     o += (size_t)(NBIN / XG) * 6 * 4;
    float* mn = (float*)(ws + o);           o += (size_t)B * 3 * 4;
    float* mx = (float*)(ws + o);           o += (size_t)B * 3 * 4;
    size_t need = o;

    int swz = (B % 8 == 0) ? 1 : 0;

    // Gate: exact bench shape (B=16, N=262144): one 8192-pt flush per block,
    // 32 segments per batch, 512-bin batches.
    bool ok = B > 0 && NB % B == 0 && bpblk == 32 && P == NB * SC
              && N == bpblk * SC && ws_size >= need;

    if (ok) {
        // every ws byte used is fully overwritten each call -> no memsets
        // despite 0xAA re-poison.
        place_kernel<<<NB, PT, 0, stream>>>(fea, xy, keyA, meta, swz);
        rowreduce_kernel<<<NBIN / XG, 512, 0, stream>>>(keyA, meta,
                                                        (float*)d_out, partials,
                                                        bpblk);
        reduce_kernel<<<B * 6, 256, 0, stream>>>(partials, mn, mx, GXC / XG);
    } else {
        float* mn_f = (float*)ws;
        float* mx_f = (float*)(ws + 256);
        float* part_f = (float*)(ws + 512);
        size_t hdr = 512 + (size_t)B * BPB * 6 * 4;
        unsigned long long* keys = (unsigned long long*)(ws + hdr);
        unsigned char* cntB = (unsigned char*)(ws + hdr + (size_t)S * 8);
        mn = mn_f; mx = mx_f;
        (void)hipMemsetAsync(keys, 0x00, (size_t)S * 9, stream);
        scatter_fb<<<(P + 255) / 256, 256, 0, stream>>>(fea, xy, keys,
                                                        (unsigned*)cntB, N, P);
        fill_fb<<<S / 256, 256, 0, stream>>>(keys, cntB, (float*)d_out, part_f);
        reduce_kernel<<<B * 6, 256, 0, stream>>>(part_f, mn_f, mx_f, BPB);
    }
    norm_kernel<<<(out_size / 4 + 255) / 256, 256, 0, stream>>>((v4f*)d_out,
                                                                mn, mx, out_size / 4);
}

// Round 5
// 166.021 us; speedup vs baseline: 1.2530x; 1.0080x over previous
//
#include <hip/hip_runtime.h>
#include <stdint.h>

#define GXC 512
#define GYC 512
#define GXY (GXC * GYC)     // 262144 voxels per batch
#define NB  512             // place blocks
#define SC  8192            // points per block = one flush (FPB=1)
#define PT  1024            // place threads per block
#define SPT (SC / PT)       // staged points per thread = 8
#define LBINS 512           // local bins = GXC (chunk stays inside one batch)
#define XG  4               // bins per rowreduce block
#define BPB (GXY / 256)     // fallback fill blocks per batch = 1024

typedef float v4f __attribute__((ext_vector_type(4)));
typedef int   v2i __attribute__((ext_vector_type(2)));

// ---- monotone float <-> sortable-uint mapping ----
__device__ __forceinline__ unsigned f2s(float f) {
    unsigned u = __float_as_uint(f);
    return (u & 0x80000000u) ? ~u : (u | 0x80000000u);
}
__device__ __forceinline__ float s2f(unsigned u) {
    return (u & 0x80000000u) ? __uint_as_float(u ^ 0x80000000u)
                             : __uint_as_float(~u);
}
// Primary-path key: [ f2s(z) : 32 | f2s(r) top 23 bits | y : 9 ].
__device__ __forceinline__ unsigned long long packkey_y(float z, float r,
                                                        unsigned y) {
    return ((unsigned long long)f2s(z) << 32)
         | (unsigned long long)((f2s(r) & ~511u) | y);
}
// Fallback key (R4 scheme): z | full r.
__device__ __forceinline__ unsigned long long packkey(float z, float r) {
    return ((unsigned long long)f2s(z) << 32) | (unsigned long long)f2s(r);
}

// XCD swizzle (locality heuristic ONLY — correctness never depends on it).
__device__ __forceinline__ int swizzle(int g, int swz) {
    return swz ? ((g & 7) * (NB / 8) + (g >> 3)) : g;
}

// ================= primary (atomic-free, histogram-free) path =================

// K1: placement into PRIVATE per-block segments (one 8192-pt flush per block).
// UNCHANGED (A/A-verified 167.3) for clean attribution.
__global__ __launch_bounds__(1024)
void place_kernel(const v4f* __restrict__ fea, const v2i* __restrict__ xy,
                  unsigned long long* __restrict__ keyA,
                  unsigned* __restrict__ meta, int swz) {
    __shared__ unsigned long long skey[SC];       // 64 KB
    __shared__ unsigned lcnt[LBINS], loff[LBINS]; // 4 KB
    __shared__ unsigned wsum[8];
    int t = threadIdx.x;
    int blk = swizzle(blockIdx.x, swz);
    int start = blk * SC;
    if (t < LBINS) lcnt[t] = 0;
    __syncthreads();

    // read + rank (SPT slots -> registers); P % (NB*SC) == 0 -> no bounds check
    unsigned long long k[SPT]; unsigned lb[SPT], rk[SPT];
    #pragma unroll
    for (int kk = 0; kk < SPT; ++kk) {
        int p = start + t + kk * PT;
        v2i q = __builtin_nontemporal_load(xy + p);
        v4f ff = __builtin_nontemporal_load(fea + p);
        k[kk]  = packkey_y(ff.z, ff.w, (unsigned)q.y);
        lb[kk] = (unsigned)q.x;
        rk[kk] = atomicAdd(&lcnt[q.x], 1u);
    }
    __syncthreads();

    // exclusive scan of lcnt[512] using first 512 threads (8 waves)
    unsigned c = 0, inc = 0;
    if (t < LBINS) {
        c = lcnt[t];
        inc = c;
        int lane = t & 63;
        #pragma unroll
        for (int off = 1; off < 64; off <<= 1) {
            unsigned o = __shfl_up(inc, off);
            if (lane >= off) inc += o;
        }
        if (lane == 63) wsum[t >> 6] = inc;
    }
    __syncthreads();
    if (t < 8) {
        unsigned v = wsum[t], i2 = v;
        #pragma unroll
        for (int off = 1; off < 8; off <<= 1) {
            unsigned o = __shfl_up(i2, off, 8);
            if (t >= off) i2 += o;
        }
        wsum[t] = i2 - v;                         // exclusive wave offsets
    }
    __syncthreads();
    if (t < LBINS) loff[t] = inc - c + wsum[t >> 6];
    __syncthreads();

    // stage bin-grouped
    #pragma unroll
    for (int kk = 0; kk < SPT; ++kk)
        skey[loff[lb[kk]] + rk[kk]] = k[kk];
    __syncthreads();

    // flush: sequential coalesced stores + packed metadata
    unsigned long long* dst = keyA + (size_t)blk * SC;
    #pragma unroll
    for (int kk = 0; kk < SPT; ++kk) {
        int s = t + kk * PT;
        dst[s] = skey[s];
    }
    if (t < LBINS)
        meta[(size_t)blk * LBINS + t] = (loff[t] << 16) | lcnt[t];
}

// K2: one block per (batch, 4 consecutive x bins); contiguous per-segment
// slices gathered by 16 lanes each; LDS max/count over 4x512 y-slots; fused
// fill with 8 KB-contiguous channel writes.
// R5: partials written TRANSPOSED as [slot][min/max][128 xg] so K4 can
// redundantly reduce its own slot's two contiguous 512 B columns (K3 deleted).
__global__ __launch_bounds__(512)
void rowreduce_kernel(const unsigned long long* __restrict__ keyA,
                      const unsigned* __restrict__ meta,
                      float* __restrict__ out,
                      float* __restrict__ partials,
                      int bpblk) {
    __shared__ unsigned long long sk[XG * 512];   // 16 KB
    __shared__ unsigned scnt[XG * 512];           // 8 KB
    __shared__ float red[8][6];
    int t = threadIdx.x;
    int g = blockIdx.x;
    int batch = g >> 7;                           // 128 x-groups per batch
    int xg = g & 127;
    int x0 = xg * XG;
    for (int i = t; i < XG * 512; i += 512) { sk[i] = 0; scnt[i] = 0; }
    __syncthreads();

    // 512 threads / 32 segments = 16 lanes per segment
    int seg = t >> 4, l16 = t & 15;
    size_t sidx = (size_t)(batch * bpblk + seg);  // FPB == 1
    uint4 m = *(const uint4*)(meta + sidx * LBINS + x0);   // 16B-aligned
    unsigned lo0 = m.x >> 16;
    unsigned b1 = m.x & 0xFFFFu;
    unsigned b2 = b1 + (m.y & 0xFFFFu);
    unsigned b3 = b2 + (m.z & 0xFFFFu);
    unsigned tot = b3 + (m.w & 0xFFFFu);
    const unsigned long long* src = keyA + sidx * SC + lo0;
    for (unsigned r = l16; r < tot; r += 16) {
        unsigned long long k = src[r];            // contiguous slice
        int bin = (r >= b1) + (r >= b2) + (r >= b3);
        unsigned y = (unsigned)k & 511u;
        atomicMax(&sk[(bin << 9) + y], k);
        atomicAdd(&scnt[(bin << 9) + y], 1u);
    }
    __syncthreads();

    size_t ob = ((size_t)batch * 3) << 18;
    size_t xoff = (size_t)x0 << 9;
    float n0 = INFINITY, mx0 = -INFINITY, n1 = INFINITY, mx1 = -INFINITY,
          n2 = INFINITY, mx2 = -INFINITY;
    for (int i = t; i < XG * 512; i += 512) {     // i = (bin<<9)+y, row-major
        unsigned cv = scnt[i];
        float h0 = 0.0f, r = 0.0f;
        if (cv) {
            unsigned long long k = sk[i];
            h0 = s2f((unsigned)(k >> 32));
            r  = s2f((unsigned)k & ~511u);
        }
        float cf = (float)cv;
        out[ob + xoff + i] = h0;
        out[ob + (size_t)GXY + xoff + i] = r;
        out[ob + (size_t)(2 * GXY) + xoff + i] = cf;
        n0 = fminf(n0, h0); mx0 = fmaxf(mx0, h0);
        n1 = fminf(n1, r);  mx1 = fmaxf(mx1, r);
        n2 = fminf(n2, cf); mx2 = fmaxf(mx2, cf);
    }
    #pragma unroll
    for (int off = 32; off; off >>= 1) {
        n0 = fminf(n0, __shfl_down(n0, off));  mx0 = fmaxf(mx0, __shfl_down(mx0, off));
        n1 = fminf(n1, __shfl_down(n1, off));  mx1 = fmaxf(mx1, __shfl_down(mx1, off));
        n2 = fminf(n2, __shfl_down(n2, off));  mx2 = fmaxf(mx2, __shfl_down(mx2, off));
    }
    int lane = t & 63, wave = t >> 6;
    if (lane == 0) {
        red[wave][0] = n0; red[wave][1] = mx0;
        red[wave][2] = n1; red[wave][3] = mx1;
        red[wave][4] = n2; red[wave][5] = mx2;
    }
    __syncthreads();
    if (t < 6) {
        int j = t;
        float v = red[0][j];
        bool isMin = (j & 1) == 0;
        #pragma unroll
        for (int w = 1; w < 8; ++w)
            v = isMin ? fminf(v, red[w][j]) : fmaxf(v, red[w][j]);
        // transposed: slot = batch*3 + channel; [slot][isMax][xg]
        int slot = batch * 3 + (j >> 1);
        partials[(size_t)slot * 256 + (j & 1) * 128 + xg] = v;
    }
}

// K4fused (primary): per-block redundant reduce of its slot's 128 min +
// 128 max partials (two contiguous 512 B columns, L2-resident), then
// in-place (v - mn) / (mx - mn).  Replaces K3 + old K4 with ONE dispatch.
// Grid is exact (gate guarantees total4 % 256 == 0) -> no early return,
// all threads reach the barrier.
// fminf/fmaxf are exactly associative -> bitwise-identical mn/mx vs K3.
__global__ __launch_bounds__(256)
void norm_fused_kernel(v4f* __restrict__ out,
                       const float* __restrict__ partials) {
    __shared__ float red4[4];
    int t = threadIdx.x;
    int i = blockIdx.x * 256 + t;
    int slot = i >> 16;                           // 65536 v4f per slot
    // threads 0-127 hold the min column, 128-255 the max column
    float v = partials[(size_t)slot * 256 + t];
    bool isMax = t >= 128;
    #pragma unroll
    for (int off = 32; off; off >>= 1) {
        float o = __shfl_down(v, off);
        v = isMax ? fmaxf(v, o) : fminf(v, o);
    }
    if ((t & 63) == 0) red4[t >> 6] = v;
    __syncthreads();
    float lo  = fminf(red4[0], red4[1]);
    float inv = 1.0f / (fmaxf(red4[2], red4[3]) - lo);
    v4f x = __builtin_nontemporal_load(out + i);
    x.x = (x.x - lo) * inv;
    x.y = (x.y - lo) * inv;
    x.z = (x.z - lo) * inv;
    x.w = (x.w - lo) * inv;
    __builtin_nontemporal_store(x, out + i);
}

// ================= fallback-path kernels (proven, unchanged) =================
__global__ void reduce_kernel(const float* __restrict__ partials,
                              float* __restrict__ mn,
                              float* __restrict__ mx,
                              int rows) {
    int b = blockIdx.x / 6;
    int j = blockIdx.x - b * 6;
    bool isMin = (j & 1) == 0;
    float v = isMin ? INFINITY : -INFINITY;
    for (int i = threadIdx.x; i < rows; i += blockDim.x) {
        float p = partials[((size_t)b * rows + i) * 6 + j];
        v = isMin ? fminf(v, p) : fmaxf(v, p);
    }
    #pragma unroll
    for (int off = 32; off; off >>= 1) {
        float o = __shfl_down(v, off);
        v = isMin ? fminf(v, o) : fmaxf(v, o);
    }
    __shared__ float red[4];
    int lane = threadIdx.x & 63, wave = threadIdx.x >> 6;
    if (lane == 0) red[wave] = v;
    __syncthreads();
    if (threadIdx.x == 0) {
        #pragma unroll
        for (int w = 1; w < 4 && w < (int)(blockDim.x >> 6); ++w)
            v = isMin ? fminf(v, red[w]) : fmaxf(v, red[w]);
        int slot = b * 3 + (j >> 1);
        if (isMin) mn[slot] = v; else mx[slot] = v;
    }
}

__global__ void norm_kernel(v4f* __restrict__ out,
                            const float* __restrict__ mn,
                            const float* __restrict__ mx,
                            int total4) {
    int i = blockIdx.x * blockDim.x + threadIdx.x;
    if (i >= total4) return;
    int slot = i >> 16;
    float lo = mn[slot];
    float inv = 1.0f / (mx[slot] - lo);
    v4f v = __builtin_nontemporal_load(out + i);
    v.x = (v.x - lo) * inv;
    v.y = (v.y - lo) * inv;
    v.z = (v.z - lo) * inv;
    v.w = (v.w - lo) * inv;
    __builtin_nontemporal_store(v, out + i);
}

__global__ void scatter_fb(const v4f* __restrict__ fea, const v2i* __restrict__ xy,
                           unsigned long long* __restrict__ keys,
                           unsigned* __restrict__ cnt32, int N, int P) {
    int p = blockIdx.x * blockDim.x + threadIdx.x;
    if (p >= P) return;
    v2i q = __builtin_nontemporal_load(xy + p);
    v4f f = __builtin_nontemporal_load(fea + p);
    int vid = ((p / N) * GXC + q.x) * GYC + q.y;
    atomicMax(&keys[vid], packkey(f.z, f.w));
    atomicAdd(&cnt32[vid >> 2], 1u << ((vid & 3) * 8));
}

__global__ void fill_fb(const unsigned long long* __restrict__ keys,
                        const unsigned char* __restrict__ cntB,
                        float* __restrict__ out, float* __restrict__ partials) {
    int g = blockIdx.x;
    int batch = g / BPB, blkInB = g - batch * BPB;
    int rem = blkInB * 256 + threadIdx.x;
    int s = batch * GXY + rem;
    unsigned c = cntB[s];
    float h0 = 0.0f, r = 0.0f;
    if (c) {
        unsigned long long k = keys[s];
        h0 = s2f((unsigned)(k >> 32));
        r  = s2f((unsigned)(k & 0xFFFFFFFFull));
    }
    float cf = (float)c;
    size_t base = (size_t)batch * 3 * GXY + rem;
    out[base] = h0; out[base + GXY] = r; out[base + 2 * GXY] = cf;
    float n0 = h0, x0 = h0, n1 = r, x1 = r, n2 = cf, x2 = cf;
    #pragma unroll
    for (int off = 32; off; off >>= 1) {
        n0 = fminf(n0, __shfl_down(n0, off)); x0 = fmaxf(x0, __shfl_down(x0, off));
        n1 = fminf(n1, __shfl_down(n1, off)); x1 = fmaxf(x1, __shfl_down(x1, off));
        n2 = fminf(n2, __shfl_down(n2, off)); x2 = fmaxf(x2, __shfl_down(x2, off));
    }
    __shared__ float red[4][6];
    int lane = threadIdx.x & 63, wave = threadIdx.x >> 6;
    if (lane == 0) {
        red[wave][0] = n0; red[wave][1] = x0; red[wave][2] = n1;
        red[wave][3] = x1; red[wave][4] = n2; red[wave][5] = x2;
    }
    __syncthreads();
    if (threadIdx.x < 6) {
        int j = threadIdx.x;
        float v = red[0][j];
        bool isMin = (j & 1) == 0;
        #pragma unroll
        for (int w = 1; w < 4; ++w)
            v = isMin ? fminf(v, red[w][j]) : fmaxf(v, red[w][j]);
        partials[(size_t)(batch * BPB + blkInB) * 6 + j] = v;
    }
}

extern "C" void kernel_launch(void* const* d_in, const int* in_sizes, int n_in,
                              void* d_out, int out_size, void* d_ws, size_t ws_size,
                              hipStream_t stream) {
    const v4f* fea = (const v4f*)d_in[0];   // [B, N, 4] f32
    const v2i* xy  = (const v2i*)d_in[1];   // [B, N, 2] i32

    int P = in_sizes[0] / 4;
    int B = out_size / (3 * GXY);
    int N = (B > 0) ? P / B : 0;
    int S = B * GXY;
    int NBIN = B * GXC;
    int bpblk = (B > 0) ? NB / B : 0;       // place blocks (=segments) per batch

    char* ws = (char*)d_ws;
    unsigned long long* keyA = (unsigned long long*)ws;
    size_t o = (size_t)P * 8;
    unsigned* meta = (unsigned*)(ws + o);   o += (size_t)NB * LBINS * 4;
    float* partials = (float*)(ws + o);     o += (size_t)(NBIN / XG) * 6 * 4;
    size_t need = o;

    int swz = (B % 8 == 0) ? 1 : 0;

    // Gate: exact bench shape (B=16, N=262144): one 8192-pt flush per block,
    // 32 segments per batch, 512-bin batches; out_size/4 % 256 == 0 so
    // norm_fused's grid is exact (no early-return before its barrier).
    bool ok = B > 0 && NB % B == 0 && bpblk == 32 && P == NB * SC
              && N == bpblk * SC && ws_size >= need
              && (out_size / 4) % 256 == 0;

    if (ok) {
        // every ws byte used is fully overwritten each call -> no memsets
        // despite 0xAA re-poison (partials fully written by K2 before K4).
        place_kernel<<<NB, PT, 0, stream>>>(fea, xy, keyA, meta, swz);
        rowreduce_kernel<<<NBIN / XG, 512, 0, stream>>>(keyA, meta,
                                                        (float*)d_out, partials,
                                                        bpblk);
        norm_fused_kernel<<<out_size / 4 / 256, 256, 0, stream>>>((v4f*)d_out,
                                                                  partials);
    } else {
        float* mn_f = (float*)ws;
        float* mx_f = (float*)(ws + 256);
        float* part_f = (float*)(ws + 512);
        size_t hdr = 512 + (size_t)B * BPB * 6 * 4;
        unsigned long long* keys = (unsigned long long*)(ws + hdr);
        unsigned char* cntB = (unsigned char*)(ws + hdr + (size_t)S * 8);
        (void)hipMemsetAsync(keys, 0x00, (size_t)S * 9, stream);
        scatter_fb<<<(P + 255) / 256, 256, 0, stream>>>(fea, xy, keys,
                                                        (unsigned*)cntB, N, P);
        fill_fb<<<S / 256, 256, 0, stream>>>(keys, cntB, (float*)d_out, part_f);
        reduce_kernel<<<B * 6, 256, 0, stream>>>(part_f, mn_f, mx_f, BPB);
        norm_kernel<<<(out_size / 4 + 255) / 256, 256, 0, stream>>>((v4f*)d_out,
                                                                    mn_f, mx_f,
                                                                    out_size / 4);
    }
}